// Round 2
// baseline (6632.667 us; speedup 1.0000x reference)
//
#include <hip/hip_runtime.h>
#include <math.h>

// Problem constants: B=16, T=64, V=50257, E=512, H=1024, L=2
#define Bc 16
#define Tc 64
#define Vc 50257
#define Ec 512
#define Hc 1024
#define SCAN_BLOCKS 256

typedef __attribute__((ext_vector_type(4))) float f32x4;
typedef __attribute__((ext_vector_type(8))) __bf16 bf16x8;

__device__ __forceinline__ float dot4(float4 a, float4 b) {
    return a.x * b.x + a.y * b.y + a.z * b.z + a.w * b.w;
}
__device__ __forceinline__ float sigm(float x) { return 1.0f / (1.0f + expf(-x)); }

// round-to-nearest-even float -> bf16 bits (finite inputs)
__device__ __forceinline__ unsigned short f2b(float f) {
    unsigned u = __float_as_uint(f);
    unsigned r = u + 0x7fffu + ((u >> 16) & 1u);
    return (unsigned short)(r >> 16);
}
__device__ __forceinline__ float b2f(unsigned short b) {
    return __uint_as_float(((unsigned)b) << 16);
}

// ---------------------------------------------------------------------------
// split fp32 -> (hi, lo) bf16 pair, 4 elements/thread
// ---------------------------------------------------------------------------
__global__ __launch_bounds__(256) void split_bf16_4(const float4* __restrict__ x,
                                                    ushort4* __restrict__ hi,
                                                    ushort4* __restrict__ lo, int n4) {
    int i = blockIdx.x * 256 + threadIdx.x;
    for (; i < n4; i += gridDim.x * 256) {
        float4 v = x[i];
        ushort4 h, l;
        h.x = f2b(v.x); l.x = f2b(v.x - b2f(h.x));
        h.y = f2b(v.y); l.y = f2b(v.y - b2f(h.y));
        h.z = f2b(v.z); l.z = f2b(v.z - b2f(h.z));
        h.w = f2b(v.w); l.w = f2b(v.w - b2f(h.w));
        hi[i] = h;
        lo[i] = l;
    }
}

// ---------------------------------------------------------------------------
// Build X0 (T*B, 2E): row m=t*B+b; cols [0,512)=emb[helper[b,t]], [512,1024)=init[b]
// ---------------------------------------------------------------------------
__global__ __launch_bounds__(256) void build_x0(const float* __restrict__ emb,
                                                const int* __restrict__ helper,
                                                const float* __restrict__ init,
                                                float* __restrict__ X0) {
    int idx = blockIdx.x * 256 + threadIdx.x;
    const int total = Tc * Bc * 1024;
    for (int i = idx; i < total; i += gridDim.x * 256) {
        int m = i >> 10;
        int c = i & 1023;
        int t = m >> 4;
        int b = m & 15;
        float v;
        if (c < 512) {
            int w = helper[b * Tc + t];
            v = emb[(size_t)w * Ec + c];
        } else {
            v = init[b * Ec + (c - 512)];
        }
        X0[i] = v;
    }
}

// ---------------------------------------------------------------------------
// h0 one-step GRU with zero initial state. dup=1 -> input row is [init;init]
// writes h0out (B, H)
// ---------------------------------------------------------------------------
__global__ __launch_bounds__(256) void h0_layer(const float* __restrict__ xin,
                                                const float* __restrict__ Wih,
                                                const float* __restrict__ bih,
                                                const float* __restrict__ bhh,
                                                float* __restrict__ h0out, int dup) {
    __shared__ float xs[1024];
    int b = blockIdx.x >> 2;
    int hseg = blockIdx.x & 3;
    int tid = threadIdx.x;
    for (int i = tid; i < 1024; i += 256)
        xs[i] = dup ? xin[b * 512 + (i & 511)] : xin[b * 1024 + i];
    __syncthreads();
    int hidx = hseg * 256 + tid;
    const float* wr = Wih + (size_t)hidx * 1024;
    const float* wz = Wih + (size_t)(Hc + hidx) * 1024;
    const float* wn = Wih + (size_t)(2 * Hc + hidx) * 1024;
    float ar = 0.f, az = 0.f, an = 0.f;
    for (int k = 0; k < 1024; k += 4) {
        float4 x4 = *(const float4*)&xs[k];
        ar += dot4(*(const float4*)&wr[k], x4);
        az += dot4(*(const float4*)&wz[k], x4);
        an += dot4(*(const float4*)&wn[k], x4);
    }
    float r = sigm(ar + bih[hidx] + bhh[hidx]);
    float z = sigm(az + bih[Hc + hidx] + bhh[Hc + hidx]);
    float n = tanhf(an + bih[2 * Hc + hidx] + r * bhh[2 * Hc + hidx]);
    h0out[b * Hc + hidx] = (1.f - z) * n;  // h_old = 0
}

// ---------------------------------------------------------------------------
// Fused 64-step GRU scan for one layer. 256 blocks x 256 threads, all
// co-resident (1 block/CU capacity-guaranteed). Block k owns h-indices
// [4k, 4k+4); its 12 W_hh rows live in LDS for the whole scan. Steps are
// separated by a monotonic device-scope barrier + agent fences (cross-XCD
// h exchange goes through L3).
// ys: slot s at ys + s*16384 (slot 0 = h0, slot t+1 = h after step t).
// ---------------------------------------------------------------------------
__device__ __forceinline__ void gbar(unsigned* cnt, unsigned target) {
    __syncthreads();
    __threadfence();  // release: h stores visible device-wide
    if (threadIdx.x == 0) {
        __hip_atomic_fetch_add(cnt, 1u, __ATOMIC_RELAXED, __HIP_MEMORY_SCOPE_AGENT);
        while (__hip_atomic_load(cnt, __ATOMIC_RELAXED, __HIP_MEMORY_SCOPE_AGENT) < target)
            __builtin_amdgcn_s_sleep(8);
    }
    __syncthreads();
    __threadfence();  // acquire: invalidate stale L1/L2 before reading new h
}

__global__ __launch_bounds__(256) void gru_scan(const float* __restrict__ xp,
                                                const float* __restrict__ Whh,
                                                const float* __restrict__ bhh,
                                                float* __restrict__ ys,
                                                unsigned* __restrict__ bar) {
    __shared__ float wlds[12][1024];  // [hl*3+gate][k]  48 KB
    __shared__ float redS[12][256];   // partial sums    12 KB
    __shared__ float xs[192];         // xp stage: [hl*3+gate][b]
    int tid = threadIdx.x;
    int g0 = blockIdx.x * 4;

    // load 12 weight rows (gate-major: row = gate*H + g0+hl) into LDS
    for (int r = 0; r < 12; ++r) {
        int hl = r / 3, gate = r % 3;
        const float4* src = (const float4*)&Whh[(size_t)(gate * Hc + g0 + hl) * Hc];
        ((float4*)wlds[r])[tid] = src[tid];
    }

    int b = tid & 15;
    int kseg = tid >> 4;  // 0..15, 64 floats each
    // per-reducer-thread constants
    float bh_r = 0.f, bh_z = 0.f, bh_n = 0.f;
    int gi = 0;
    if (tid < 64) {
        gi = g0 + (tid >> 4);
        bh_r = bhh[gi];
        bh_z = bhh[Hc + gi];
        bh_n = bhh[2 * Hc + gi];
    }
    __syncthreads();

    for (int t = 0; t < Tc; ++t) {
        // stage this step's xp gate values (includes b_ih from the GEMM)
        if (tid < 192) {
            int r = tid >> 4, bb = tid & 15;
            int hl = r / 3, gate = r % 3;
            xs[tid] = xp[(size_t)(t * Bc + bb) * (3 * Hc) + gate * Hc + g0 + hl];
        }
        // load fresh h slice (64 floats) and MAC against LDS weights
        const float4* hp = (const float4*)(ys + (size_t)t * (Bc * Hc) + b * Hc + kseg * 64);
        float4 hv[16];
#pragma unroll
        for (int i = 0; i < 16; ++i) hv[i] = hp[i];
#pragma unroll
        for (int r = 0; r < 12; ++r) {
            const float4* w = (const float4*)&wlds[r][kseg * 64];
            float s = 0.f;
#pragma unroll
            for (int i = 0; i < 16; ++i) s += dot4(w[i], hv[i]);
            redS[r][tid] = s;
        }
        __syncthreads();
        if (tid < 64) {
            int hl = tid >> 4, bb = tid & 15;
            float sr = 0.f, sz = 0.f, sn = 0.f;
            for (int ks = 0; ks < 16; ++ks) {
                sr += redS[hl * 3 + 0][ks * 16 + bb];
                sz += redS[hl * 3 + 1][ks * 16 + bb];
                sn += redS[hl * 3 + 2][ks * 16 + bb];
            }
            float r_ = sigm(xs[(hl * 3 + 0) * 16 + bb] + sr + bh_r);
            float z_ = sigm(xs[(hl * 3 + 1) * 16 + bb] + sz + bh_z);
            float n_ = tanhf(xs[(hl * 3 + 2) * 16 + bb] + r_ * (sn + bh_n));
            float hold = ys[(size_t)t * (Bc * Hc) + bb * Hc + gi];
            float hnew = (1.f - z_) * n_ + z_ * hold;
            ys[(size_t)(t + 1) * (Bc * Hc) + bb * Hc + gi] = hnew;
        }
        if (t < Tc - 1) gbar(bar, (unsigned)((t + 1) * SCAN_BLOCKS));
        else __syncthreads();
    }
}

// ---------------------------------------------------------------------------
// Split-bf16 MFMA GEMM (fp32-accurate): C = act( A @ B^T + bias ), where
// A = Ah + Al, B = Bh + Bl and C = Ah Bh + Ah Bl + Al Bh (3 phases).
// A: (1024, K) row-major bf16 pair; B: (N, K) row-major bf16 pair.
// 128x128 tile, BK=32, 4 waves in 2x2, 16x16x32 bf16 MFMA.
// remap=1: output row m=t*B+b stored at row b*T+t. N edge guarded.
// ---------------------------------------------------------------------------
#define GLD_LDS16(g, l)                                                        \
    __builtin_amdgcn_global_load_lds(                                          \
        (const __attribute__((address_space(1))) unsigned int*)(g),            \
        (__attribute__((address_space(3))) unsigned int*)(l), 16, 0, 0)

__global__ __launch_bounds__(256) void mfma_gemm_split(
    const unsigned short* __restrict__ Ah, const unsigned short* __restrict__ Al,
    const unsigned short* __restrict__ Bh, const unsigned short* __restrict__ Bl,
    const float* __restrict__ bias, float* __restrict__ C, int N, int K, int ldc,
    int act, int remap) {
    __shared__ __align__(16) unsigned short As[128 * 32];  // [m][k] 8 KB
    __shared__ __align__(16) unsigned short Bs[128 * 32];  // [n][k] 8 KB
    int tid = threadIdx.x;
    int m0 = blockIdx.y * 128, n0 = blockIdx.x * 128;
    int wave = tid >> 6, lane = tid & 63;
    int mh = (wave >> 1) * 64, nh = (wave & 1) * 64;
    int rlane = lane & 15, k8 = (lane >> 4) * 8;

    f32x4 zero = {0.f, 0.f, 0.f, 0.f};
    f32x4 acc[4][4];
#pragma unroll
    for (int i = 0; i < 4; ++i)
#pragma unroll
        for (int j = 0; j < 4; ++j) acc[i][j] = zero;

    const unsigned short* Ap[3] = {Ah, Al, Ah};
    const unsigned short* Bp[3] = {Bh, Bh, Bl};

    // staging chunks: c = tid + h*256 ; row = c>>2, koff = (c&3)*8
    int c0 = tid, c1 = tid + 256;
    int ar0 = m0 + (c0 >> 2), ak0 = (c0 & 3) * 8;
    int ar1 = m0 + (c1 >> 2), ak1 = (c1 & 3) * 8;
    int br0 = n0 + (c0 >> 2);
    int br1 = n0 + (c1 >> 2);
    if (br0 >= N) br0 = N - 1;
    if (br1 >= N) br1 = N - 1;

    for (int ph = 0; ph < 3; ++ph) {
        const unsigned short* Ab = Ap[ph];
        const unsigned short* Bb = Bp[ph];
        for (int kt = 0; kt < K; kt += 32) {
            GLD_LDS16(&Ab[(size_t)ar0 * K + kt + ak0], &As[c0 * 8]);
            GLD_LDS16(&Ab[(size_t)ar1 * K + kt + ak1], &As[c1 * 8]);
            GLD_LDS16(&Bb[(size_t)br0 * K + kt + ak0], &Bs[c0 * 8]);
            GLD_LDS16(&Bb[(size_t)br1 * K + kt + ak1], &Bs[c1 * 8]);
            __syncthreads();
            bf16x8 a[4], b[4];
#pragma unroll
            for (int f = 0; f < 4; ++f)
                a[f] = *(const bf16x8*)&As[(mh + f * 16 + rlane) * 32 + k8];
#pragma unroll
            for (int f = 0; f < 4; ++f)
                b[f] = *(const bf16x8*)&Bs[(nh + f * 16 + rlane) * 32 + k8];
#pragma unroll
            for (int mf = 0; mf < 4; ++mf)
#pragma unroll
                for (int nf = 0; nf < 4; ++nf)
                    acc[mf][nf] = __builtin_amdgcn_mfma_f32_16x16x32_bf16(
                        a[mf], b[nf], acc[mf][nf], 0, 0, 0);
            __syncthreads();
        }
    }

    // epilogue: C/D layout col=lane&15, row=(lane>>4)*4+reg
    int quad = lane >> 4;
#pragma unroll
    for (int nf = 0; nf < 4; ++nf) {
        int n = n0 + nh + nf * 16 + rlane;
        if (n >= N) continue;
        float bv = bias ? bias[n] : 0.f;
#pragma unroll
        for (int mf = 0; mf < 4; ++mf) {
#pragma unroll
            for (int r = 0; r < 4; ++r) {
                int m = m0 + mh + mf * 16 + quad * 4 + r;
                float x = acc[mf][nf][r] + bv;
                if (act) x = tanhf(x);
                int orow = remap ? ((m & 15) * Tc + (m >> 4)) : m;
                C[(size_t)orow * ldc + n] = x;
            }
        }
    }
}

// ---------------------------------------------------------------------------
extern "C" void kernel_launch(void* const* d_in, const int* in_sizes, int n_in,
                              void* d_out, int out_size, void* d_ws, size_t ws_size,
                              hipStream_t stream) {
    const float* init   = (const float*)d_in[0];
    const int*   helper = (const int*)d_in[1];
    const float* emb    = (const float*)d_in[2];
    const float* W_ih0  = (const float*)d_in[3];
    const float* W_hh0  = (const float*)d_in[4];
    const float* b_ih0  = (const float*)d_in[5];
    const float* b_hh0  = (const float*)d_in[6];
    const float* W_ih1  = (const float*)d_in[7];
    const float* W_hh1  = (const float*)d_in[8];
    const float* b_ih1  = (const float*)d_in[9];
    const float* b_hh1  = (const float*)d_in[10];
    const float* Wc_w   = (const float*)d_in[11];
    const float* Wc_b   = (const float*)d_in[12];
    float* out = (float*)d_out;

    const int embN = Vc * Ec;  // 25,731,584

    char* p = (char*)d_ws;
    auto alloc = [&](size_t bytes) {
        char* r = p;
        p += (bytes + 255) & ~(size_t)255;
        return r;
    };
    float* X0   = (float*)alloc((size_t)1048576 * 4);
    float* xp0  = (float*)alloc((size_t)3145728 * 4);
    float* xp1  = (float*)alloc((size_t)3145728 * 4);
    float* ys0x = (float*)alloc((size_t)65 * 16384 * 4);
    float* ys1x = (float*)alloc((size_t)65 * 16384 * 4);
    float* fin  = (float*)alloc((size_t)524288 * 4);
    unsigned* bar = (unsigned*)alloc(256);
    unsigned short* embh = (unsigned short*)alloc((size_t)embN * 2);
    unsigned short* embl = (unsigned short*)alloc((size_t)embN * 2);
    unsigned short* X0h  = (unsigned short*)alloc((size_t)1048576 * 2);
    unsigned short* X0l  = (unsigned short*)alloc((size_t)1048576 * 2);
    unsigned short* Wi0h = (unsigned short*)alloc((size_t)3145728 * 2);
    unsigned short* Wi0l = (unsigned short*)alloc((size_t)3145728 * 2);
    unsigned short* Wi1h = (unsigned short*)alloc((size_t)3145728 * 2);
    unsigned short* Wi1l = (unsigned short*)alloc((size_t)3145728 * 2);
    unsigned short* Wch  = (unsigned short*)alloc((size_t)524288 * 2);
    unsigned short* Wcl  = (unsigned short*)alloc((size_t)524288 * 2);
    unsigned short* ys0h = (unsigned short*)alloc((size_t)1048576 * 2);
    unsigned short* ys0l = (unsigned short*)alloc((size_t)1048576 * 2);
    unsigned short* ys1h = (unsigned short*)alloc((size_t)1048576 * 2);
    unsigned short* ys1l = (unsigned short*)alloc((size_t)1048576 * 2);
    unsigned short* finh = (unsigned short*)alloc((size_t)524288 * 2);
    unsigned short* finl = (unsigned short*)alloc((size_t)524288 * 2);

    hipMemsetAsync(bar, 0, 256, stream);

    auto split = [&](const float* src, unsigned short* h, unsigned short* l, int n) {
        int n4 = n / 4;
        int grid = (n4 + 255) / 256;
        if (grid > 4096) grid = 4096;
        split_bf16_4<<<grid, 256, 0, stream>>>((const float4*)src, (ushort4*)h,
                                               (ushort4*)l, n4);
    };

    // weight / emb conversions
    split(emb, embh, embl, embN);
    split(W_ih0, Wi0h, Wi0l, 3145728);
    split(W_ih1, Wi1h, Wi1l, 3145728);
    split(Wc_w, Wch, Wcl, 524288);

    // initial hidden states -> slot 0 of each ys buffer
    h0_layer<<<64, 256, 0, stream>>>(init, W_ih0, b_ih0, b_hh0, ys0x, 1);
    h0_layer<<<64, 256, 0, stream>>>(ys0x, W_ih1, b_ih1, b_hh1, ys1x, 0);

    // decode inputs, layer-0 input gates
    build_x0<<<1024, 256, 0, stream>>>(emb, helper, init, X0);
    split(X0, X0h, X0l, 1048576);
    mfma_gemm_split<<<dim3(24, 8), 256, 0, stream>>>(X0h, X0l, Wi0h, Wi0l, b_ih0,
                                                     xp0, 3072, 1024, 3072, 0, 0);
    // layer-0 scan (fused 64 steps)
    gru_scan<<<SCAN_BLOCKS, 256, 0, stream>>>(xp0, W_hh0, b_hh0, ys0x, bar + 0);

    // layer-1 input gates + scan
    split(ys0x + 16384, ys0h, ys0l, 1048576);
    mfma_gemm_split<<<dim3(24, 8), 256, 0, stream>>>(ys0h, ys0l, Wi1h, Wi1l, b_ih1,
                                                     xp1, 3072, 1024, 3072, 0, 0);
    gru_scan<<<SCAN_BLOCKS, 256, 0, stream>>>(xp1, W_hh1, b_hh1, ys1x, bar + 16);

    // final = tanh(ys1 @ Wc^T + b)
    split(ys1x + 16384, ys1h, ys1l, 1048576);
    mfma_gemm_split<<<dim3(4, 8), 256, 0, stream>>>(ys1h, ys1l, Wch, Wcl, Wc_b,
                                                    fin, 512, 1024, 512, 1, 0);

    // logits = final @ emb^T with (t,b)->(b,t) row remap
    split(fin, finh, finl, 524288);
    mfma_gemm_split<<<dim3((Vc + 127) / 128, 8), 256, 0, stream>>>(
        finh, finl, embh, embl, nullptr, out, Vc, 512, Vc, 0, 1);
}

// Round 3
// 2416.603 us; speedup vs baseline: 2.7446x; 2.7446x over previous
//
#include <hip/hip_runtime.h>
#include <math.h>

// Problem constants: B=16, T=64, V=50257, E=512, H=1024, L=2
#define Bc 16
#define Tc 64
#define Vc 50257
#define Ec 512
#define Hc 1024
#define SCAN_BLOCKS 256

typedef __attribute__((ext_vector_type(4))) float f32x4;
typedef __attribute__((ext_vector_type(8))) __bf16 bf16x8;

__device__ __forceinline__ float dot4(float4 a, float4 b) {
    return a.x * b.x + a.y * b.y + a.z * b.z + a.w * b.w;
}
__device__ __forceinline__ float sigm(float x) { return 1.0f / (1.0f + expf(-x)); }

// round-to-nearest-even float -> bf16 bits (finite inputs)
__device__ __forceinline__ unsigned short f2b(float f) {
    unsigned u = __float_as_uint(f);
    unsigned r = u + 0x7fffu + ((u >> 16) & 1u);
    return (unsigned short)(r >> 16);
}
__device__ __forceinline__ float b2f(unsigned short b) {
    return __uint_as_float(((unsigned)b) << 16);
}
__device__ __forceinline__ float2 u2f2(unsigned long long u) {
    union { unsigned long long u; float2 f; } c;
    c.u = u;
    return c.f;
}

// ---------------------------------------------------------------------------
// split fp32 -> (hi, lo) bf16 pair, 4 elements/thread
// ---------------------------------------------------------------------------
__global__ __launch_bounds__(256) void split_bf16_4(const float4* __restrict__ x,
                                                    ushort4* __restrict__ hi,
                                                    ushort4* __restrict__ lo, int n4) {
    int i = blockIdx.x * 256 + threadIdx.x;
    for (; i < n4; i += gridDim.x * 256) {
        float4 v = x[i];
        ushort4 h, l;
        h.x = f2b(v.x); l.x = f2b(v.x - b2f(h.x));
        h.y = f2b(v.y); l.y = f2b(v.y - b2f(h.y));
        h.z = f2b(v.z); l.z = f2b(v.z - b2f(h.z));
        h.w = f2b(v.w); l.w = f2b(v.w - b2f(h.w));
        hi[i] = h;
        lo[i] = l;
    }
}

// ---------------------------------------------------------------------------
// Build X0 (T*B, 2E): row m=t*B+b; cols [0,512)=emb[helper[b,t]], [512,1024)=init[b]
// ---------------------------------------------------------------------------
__global__ __launch_bounds__(256) void build_x0(const float* __restrict__ emb,
                                                const int* __restrict__ helper,
                                                const float* __restrict__ init,
                                                float* __restrict__ X0) {
    int idx = blockIdx.x * 256 + threadIdx.x;
    const int total = Tc * Bc * 1024;
    for (int i = idx; i < total; i += gridDim.x * 256) {
        int m = i >> 10;
        int c = i & 1023;
        int t = m >> 4;
        int b = m & 15;
        float v;
        if (c < 512) {
            int w = helper[b * Tc + t];
            v = emb[(size_t)w * Ec + c];
        } else {
            v = init[b * Ec + (c - 512)];
        }
        X0[i] = v;
    }
}

// ---------------------------------------------------------------------------
// h0 one-step GRU with zero initial state. dup=1 -> input row is [init;init]
// ---------------------------------------------------------------------------
__global__ __launch_bounds__(256) void h0_layer(const float* __restrict__ xin,
                                                const float* __restrict__ Wih,
                                                const float* __restrict__ bih,
                                                const float* __restrict__ bhh,
                                                float* __restrict__ h0out, int dup) {
    __shared__ float xs[1024];
    int b = blockIdx.x >> 2;
    int hseg = blockIdx.x & 3;
    int tid = threadIdx.x;
    for (int i = tid; i < 1024; i += 256)
        xs[i] = dup ? xin[b * 512 + (i & 511)] : xin[b * 1024 + i];
    __syncthreads();
    int hidx = hseg * 256 + tid;
    const float* wr = Wih + (size_t)hidx * 1024;
    const float* wz = Wih + (size_t)(Hc + hidx) * 1024;
    const float* wn = Wih + (size_t)(2 * Hc + hidx) * 1024;
    float ar = 0.f, az = 0.f, an = 0.f;
    for (int k = 0; k < 1024; k += 4) {
        float4 x4 = *(const float4*)&xs[k];
        ar += dot4(*(const float4*)&wr[k], x4);
        az += dot4(*(const float4*)&wz[k], x4);
        an += dot4(*(const float4*)&wn[k], x4);
    }
    float r = sigm(ar + bih[hidx] + bhh[hidx]);
    float z = sigm(az + bih[Hc + hidx] + bhh[Hc + hidx]);
    float n = tanhf(an + bih[2 * Hc + hidx] + r * bhh[2 * Hc + hidx]);
    h0out[b * Hc + hidx] = (1.f - z) * n;  // h_old = 0
}

// ---------------------------------------------------------------------------
// Fused 64-step GRU scan. 256 blocks (1/CU), block owns h-indices [4k,4k+4);
// W_hh rows (48 KB) resident in LDS. NO __threadfence: h exchanged through
// L3 via agent-scope relaxed atomics (sc0 sc1 — bypass non-coherent L1/L2);
// barrier = relaxed fetch_add + spin. __syncthreads drains vmcnt before the
// arrive, so sc1 h-stores are globally visible when the counter ticks.
// Threads are b-major (b=tid>>4, kseg=tid&15): coalesced h loads, and
// ds_read_b64 of W covers all 32 banks exactly (conflict-free).
// ys: slot s at ys + s*16384 (slot 0 = h0, slot t+1 = h after step t).
// ---------------------------------------------------------------------------
__device__ __forceinline__ void gbar(unsigned* cnt, unsigned target) {
    __syncthreads();  // emits s_waitcnt vmcnt(0) before s_barrier: stores drained
    if (threadIdx.x == 0) {
        __hip_atomic_fetch_add(cnt, 1u, __ATOMIC_RELAXED, __HIP_MEMORY_SCOPE_AGENT);
        while (__hip_atomic_load(cnt, __ATOMIC_RELAXED, __HIP_MEMORY_SCOPE_AGENT) <
               target)
            __builtin_amdgcn_s_sleep(2);
    }
    __syncthreads();
}

__global__ __launch_bounds__(256) void gru_scan(const float* __restrict__ xp,
                                                const float* __restrict__ Whh,
                                                const float* __restrict__ bhh,
                                                float* __restrict__ ys,
                                                unsigned* __restrict__ bar) {
    __shared__ float wlds[12][1024];  // [hl*3+gate][k]  48 KB
    __shared__ float redS[12][256];   // partial sums    12 KB
    __shared__ float xs[192];         // xp stage: [hl*3+gate][b]
    int tid = threadIdx.x;
    int g0 = blockIdx.x * 4;

    for (int r = 0; r < 12; ++r) {
        int hl = r / 3, gate = r % 3;
        const float4* src = (const float4*)&Whh[(size_t)(gate * Hc + g0 + hl) * Hc];
        ((float4*)wlds[r])[tid] = src[tid];
    }

    int b = tid >> 4;     // batch (slow) — 16-lane groups share b
    int kseg = tid & 15;  // k-segment (fast) — lanes consecutive in k

    float bh_r = 0.f, bh_z = 0.f, bh_n = 0.f;
    int gi = 0, rb = 0, rhl = 0;
    if (tid < 64) {
        rhl = tid >> 4;
        rb = tid & 15;
        gi = g0 + rhl;
        bh_r = bhh[gi];
        bh_z = bhh[Hc + gi];
        bh_n = bhh[2 * Hc + gi];
    }
    __syncthreads();

    for (int t = 0; t < Tc; ++t) {
        if (tid < 192) {
            int r = tid >> 4, bb = tid & 15;
            int hl = r / 3, gate = r % 3;
            xs[tid] = xp[(size_t)(t * Bc + bb) * (3 * Hc) + gate * Hc + g0 + hl];
        }
        // coherent h load: 32 x 8B per thread; 16-lane groups cover 256B runs
        const unsigned long long* hsrc =
            (const unsigned long long*)(ys + (size_t)t * (Bc * Hc)) + b * 512 + kseg;
        float2 hv[32];
#pragma unroll
        for (int q = 0; q < 32; ++q)
            hv[q] = u2f2(__hip_atomic_load(hsrc + q * 16, __ATOMIC_RELAXED,
                                           __HIP_MEMORY_SCOPE_AGENT));
        const float2* wbase = (const float2*)&wlds[0][0];
#pragma unroll
        for (int r = 0; r < 12; ++r) {
            const float2* w = wbase + r * 512 + kseg;  // float2 idx: q*16 stride
            float s = 0.f;
#pragma unroll
            for (int q = 0; q < 32; ++q) {
                float2 ww = w[q * 16];  // wlds[r][q*32 + kseg*2 .. +1]
                s += ww.x * hv[q].x + ww.y * hv[q].y;
            }
            redS[r][tid] = s;
        }
        __syncthreads();
        if (tid < 64) {
            float sr = 0.f, sz = 0.f, sn = 0.f;
            for (int ks = 0; ks < 16; ++ks) {
                int idx = rb * 16 + ks;  // writer tid with b=rb, kseg=ks
                sr += redS[rhl * 3 + 0][idx];
                sz += redS[rhl * 3 + 1][idx];
                sn += redS[rhl * 3 + 2][idx];
            }
            float r_ = sigm(xs[(rhl * 3 + 0) * 16 + rb] + sr + bh_r);
            float z_ = sigm(xs[(rhl * 3 + 1) * 16 + rb] + sz + bh_z);
            float n_ = tanhf(xs[(rhl * 3 + 2) * 16 + rb] + r_ * (sn + bh_n));
            float hold = __uint_as_float(__hip_atomic_load(
                (const unsigned*)(ys + (size_t)t * (Bc * Hc) + rb * Hc + gi),
                __ATOMIC_RELAXED, __HIP_MEMORY_SCOPE_AGENT));
            float hnew = (1.f - z_) * n_ + z_ * hold;
            __hip_atomic_store(
                (unsigned*)(ys + (size_t)(t + 1) * (Bc * Hc) + rb * Hc + gi),
                __float_as_uint(hnew), __ATOMIC_RELAXED, __HIP_MEMORY_SCOPE_AGENT);
        }
        if (t < Tc - 1) gbar(bar, (unsigned)((t + 1) * SCAN_BLOCKS));
    }
}

// ---------------------------------------------------------------------------
// Split-bf16 MFMA GEMM (fp32-accurate): C = act( A @ B^T + bias ), where
// A = Ah + Al, B = Bh + Bl and C = Ah Bh + Ah Bl + Al Bh (3 phases).
// 128x128 tile, BK=32, 4 waves in 2x2, 16x16x32 bf16 MFMA.
// remap=1: output row m=t*B+b stored at row b*T+t. N edge guarded.
// ---------------------------------------------------------------------------
#define GLD_LDS16(g, l)                                                        \
    __builtin_amdgcn_global_load_lds(                                          \
        (const __attribute__((address_space(1))) unsigned int*)(g),            \
        (__attribute__((address_space(3))) unsigned int*)(l), 16, 0, 0)

__global__ __launch_bounds__(256) void mfma_gemm_split(
    const unsigned short* __restrict__ Ah, const unsigned short* __restrict__ Al,
    const unsigned short* __restrict__ Bh, const unsigned short* __restrict__ Bl,
    const float* __restrict__ bias, float* __restrict__ C, int N, int K, int ldc,
    int act, int remap) {
    __shared__ __align__(16) unsigned short As[128 * 32];  // [m][k] 8 KB
    __shared__ __align__(16) unsigned short Bs[128 * 32];  // [n][k] 8 KB
    int tid = threadIdx.x;
    int m0 = blockIdx.y * 128, n0 = blockIdx.x * 128;
    int wave = tid >> 6, lane = tid & 63;
    int mh = (wave >> 1) * 64, nh = (wave & 1) * 64;
    int rlane = lane & 15, k8 = (lane >> 4) * 8;

    f32x4 zero = {0.f, 0.f, 0.f, 0.f};
    f32x4 acc[4][4];
#pragma unroll
    for (int i = 0; i < 4; ++i)
#pragma unroll
        for (int j = 0; j < 4; ++j) acc[i][j] = zero;

    const unsigned short* Ap[3] = {Ah, Al, Ah};
    const unsigned short* Bp[3] = {Bh, Bh, Bl};

    int c0 = tid, c1 = tid + 256;
    int ar0 = m0 + (c0 >> 2), ak0 = (c0 & 3) * 8;
    int ar1 = m0 + (c1 >> 2), ak1 = (c1 & 3) * 8;
    int br0 = n0 + (c0 >> 2);
    int br1 = n0 + (c1 >> 2);
    if (br0 >= N) br0 = N - 1;
    if (br1 >= N) br1 = N - 1;

    for (int ph = 0; ph < 3; ++ph) {
        const unsigned short* Ab = Ap[ph];
        const unsigned short* Bb = Bp[ph];
        for (int kt = 0; kt < K; kt += 32) {
            GLD_LDS16(&Ab[(size_t)ar0 * K + kt + ak0], &As[c0 * 8]);
            GLD_LDS16(&Ab[(size_t)ar1 * K + kt + ak1], &As[c1 * 8]);
            GLD_LDS16(&Bb[(size_t)br0 * K + kt + ak0], &Bs[c0 * 8]);
            GLD_LDS16(&Bb[(size_t)br1 * K + kt + ak1], &Bs[c1 * 8]);
            __syncthreads();
            bf16x8 a[4], b[4];
#pragma unroll
            for (int f = 0; f < 4; ++f)
                a[f] = *(const bf16x8*)&As[(mh + f * 16 + rlane) * 32 + k8];
#pragma unroll
            for (int f = 0; f < 4; ++f)
                b[f] = *(const bf16x8*)&Bs[(nh + f * 16 + rlane) * 32 + k8];
#pragma unroll
            for (int mf = 0; mf < 4; ++mf)
#pragma unroll
                for (int nf = 0; nf < 4; ++nf)
                    acc[mf][nf] = __builtin_amdgcn_mfma_f32_16x16x32_bf16(
                        a[mf], b[nf], acc[mf][nf], 0, 0, 0);
            __syncthreads();
        }
    }

    int quad = lane >> 4;
#pragma unroll
    for (int nf = 0; nf < 4; ++nf) {
        int n = n0 + nh + nf * 16 + rlane;
        if (n >= N) continue;
        float bv = bias ? bias[n] : 0.f;
#pragma unroll
        for (int mf = 0; mf < 4; ++mf) {
#pragma unroll
            for (int r = 0; r < 4; ++r) {
                int m = m0 + mh + mf * 16 + quad * 4 + r;
                float x = acc[mf][nf][r] + bv;
                if (act) x = tanhf(x);
                int orow = remap ? ((m & 15) * Tc + (m >> 4)) : m;
                C[(size_t)orow * ldc + n] = x;
            }
        }
    }
}

// ---------------------------------------------------------------------------
extern "C" void kernel_launch(void* const* d_in, const int* in_sizes, int n_in,
                              void* d_out, int out_size, void* d_ws, size_t ws_size,
                              hipStream_t stream) {
    const float* init   = (const float*)d_in[0];
    const int*   helper = (const int*)d_in[1];
    const float* emb    = (const float*)d_in[2];
    const float* W_ih0  = (const float*)d_in[3];
    const float* W_hh0  = (const float*)d_in[4];
    const float* b_ih0  = (const float*)d_in[5];
    const float* b_hh0  = (const float*)d_in[6];
    const float* W_ih1  = (const float*)d_in[7];
    const float* W_hh1  = (const float*)d_in[8];
    const float* b_ih1  = (const float*)d_in[9];
    const float* b_hh1  = (const float*)d_in[10];
    const float* Wc_w   = (const float*)d_in[11];
    const float* Wc_b   = (const float*)d_in[12];
    float* out = (float*)d_out;

    const int embN = Vc * Ec;

    char* p = (char*)d_ws;
    auto alloc = [&](size_t bytes) {
        char* r = p;
        p += (bytes + 255) & ~(size_t)255;
        return r;
    };
    float* X0   = (float*)alloc((size_t)1048576 * 4);
    float* xp0  = (float*)alloc((size_t)3145728 * 4);
    float* xp1  = (float*)alloc((size_t)3145728 * 4);
    float* ys0x = (float*)alloc((size_t)65 * 16384 * 4);
    float* ys1x = (float*)alloc((size_t)65 * 16384 * 4);
    float* fin  = (float*)alloc((size_t)524288 * 4);
    unsigned* bar = (unsigned*)alloc(256);
    unsigned short* embh = (unsigned short*)alloc((size_t)embN * 2);
    unsigned short* embl = (unsigned short*)alloc((size_t)embN * 2);
    unsigned short* X0h  = (unsigned short*)alloc((size_t)1048576 * 2);
    unsigned short* X0l  = (unsigned short*)alloc((size_t)1048576 * 2);
    unsigned short* Wi0h = (unsigned short*)alloc((size_t)3145728 * 2);
    unsigned short* Wi0l = (unsigned short*)alloc((size_t)3145728 * 2);
    unsigned short* Wi1h = (unsigned short*)alloc((size_t)3145728 * 2);
    unsigned short* Wi1l = (unsigned short*)alloc((size_t)3145728 * 2);
    unsigned short* Wch  = (unsigned short*)alloc((size_t)524288 * 2);
    unsigned short* Wcl  = (unsigned short*)alloc((size_t)524288 * 2);
    unsigned short* ys0h = (unsigned short*)alloc((size_t)1048576 * 2);
    unsigned short* ys0l = (unsigned short*)alloc((size_t)1048576 * 2);
    unsigned short* ys1h = (unsigned short*)alloc((size_t)1048576 * 2);
    unsigned short* ys1l = (unsigned short*)alloc((size_t)1048576 * 2);
    unsigned short* finh = (unsigned short*)alloc((size_t)524288 * 2);
    unsigned short* finl = (unsigned short*)alloc((size_t)524288 * 2);

    hipMemsetAsync(bar, 0, 256, stream);

    auto split = [&](const float* src, unsigned short* h, unsigned short* l, int n) {
        int n4 = n / 4;
        int grid = (n4 + 255) / 256;
        if (grid > 4096) grid = 4096;
        split_bf16_4<<<grid, 256, 0, stream>>>((const float4*)src, (ushort4*)h,
                                               (ushort4*)l, n4);
    };

    split(emb, embh, embl, embN);
    split(W_ih0, Wi0h, Wi0l, 3145728);
    split(W_ih1, Wi1h, Wi1l, 3145728);
    split(Wc_w, Wch, Wcl, 524288);

    h0_layer<<<64, 256, 0, stream>>>(init, W_ih0, b_ih0, b_hh0, ys0x, 1);
    h0_layer<<<64, 256, 0, stream>>>(ys0x, W_ih1, b_ih1, b_hh1, ys1x, 0);

    build_x0<<<1024, 256, 0, stream>>>(emb, helper, init, X0);
    split(X0, X0h, X0l, 1048576);
    mfma_gemm_split<<<dim3(24, 8), 256, 0, stream>>>(X0h, X0l, Wi0h, Wi0l, b_ih0,
                                                     xp0, 3072, 1024, 3072, 0, 0);
    gru_scan<<<SCAN_BLOCKS, 256, 0, stream>>>(xp0, W_hh0, b_hh0, ys0x, bar + 0);

    split(ys0x + 16384, ys0h, ys0l, 1048576);
    mfma_gemm_split<<<dim3(24, 8), 256, 0, stream>>>(ys0h, ys0l, Wi1h, Wi1l, b_ih1,
                                                     xp1, 3072, 1024, 3072, 0, 0);
    gru_scan<<<SCAN_BLOCKS, 256, 0, stream>>>(xp1, W_hh1, b_hh1, ys1x, bar + 16);

    split(ys1x + 16384, ys1h, ys1l, 1048576);
    mfma_gemm_split<<<dim3(4, 8), 256, 0, stream>>>(ys1h, ys1l, Wch, Wcl, Wc_b,
                                                    fin, 512, 1024, 512, 1, 0);

    split(fin, finh, finl, 524288);
    mfma_gemm_split<<<dim3((Vc + 127) / 128, 8), 256, 0, stream>>>(
        finh, finl, embh, embl, nullptr, out, Vc, 512, Vc, 0, 1);
}

// Round 4
// 2239.220 us; speedup vs baseline: 2.9620x; 1.0792x over previous
//
#include <hip/hip_runtime.h>
#include <math.h>

// Problem constants: B=16, T=64, V=50257, E=512, H=1024, L=2
#define Bc 16
#define Tc 64
#define Vc 50257
#define Ec 512
#define Hc 1024
#define SCAN_BLOCKS 256

typedef __attribute__((ext_vector_type(4))) float f32x4;
typedef __attribute__((ext_vector_type(8))) __bf16 bf16x8;

__device__ __forceinline__ float dot4(float4 a, float4 b) {
    return a.x * b.x + a.y * b.y + a.z * b.z + a.w * b.w;
}
__device__ __forceinline__ float sigm(float x) { return 1.0f / (1.0f + expf(-x)); }

// round-to-nearest-even float -> bf16 bits (finite inputs)
__device__ __forceinline__ unsigned short f2b(float f) {
    unsigned u = __float_as_uint(f);
    unsigned r = u + 0x7fffu + ((u >> 16) & 1u);
    return (unsigned short)(r >> 16);
}
__device__ __forceinline__ float b2f(unsigned short b) {
    return __uint_as_float(((unsigned)b) << 16);
}
__device__ __forceinline__ float2 u2f2(unsigned long long u) {
    union { unsigned long long u; float2 f; } c;
    c.u = u;
    return c.f;
}
__device__ __forceinline__ unsigned long long f22u(float a, float b) {
    union { float f[2]; unsigned long long u; } c;
    c.f[0] = a;
    c.f[1] = b;
    return c.u;
}

// ---------------------------------------------------------------------------
// split fp32 -> (hi, lo) bf16 pair, 4 elements/thread
// ---------------------------------------------------------------------------
__global__ __launch_bounds__(256) void split_bf16_4(const float4* __restrict__ x,
                                                    ushort4* __restrict__ hi,
                                                    ushort4* __restrict__ lo, int n4) {
    int i = blockIdx.x * 256 + threadIdx.x;
    for (; i < n4; i += gridDim.x * 256) {
        float4 v = x[i];
        ushort4 h, l;
        h.x = f2b(v.x); l.x = f2b(v.x - b2f(h.x));
        h.y = f2b(v.y); l.y = f2b(v.y - b2f(h.y));
        h.z = f2b(v.z); l.z = f2b(v.z - b2f(h.z));
        h.w = f2b(v.w); l.w = f2b(v.w - b2f(h.w));
        hi[i] = h;
        lo[i] = l;
    }
}

// ---------------------------------------------------------------------------
// Build X0 (T*B, 2E): row m=t*B+b; cols [0,512)=emb[helper[b,t]], [512,1024)=init[b]
// ---------------------------------------------------------------------------
__global__ __launch_bounds__(256) void build_x0(const float* __restrict__ emb,
                                                const int* __restrict__ helper,
                                                const float* __restrict__ init,
                                                float* __restrict__ X0) {
    int idx = blockIdx.x * 256 + threadIdx.x;
    const int total = Tc * Bc * 1024;
    for (int i = idx; i < total; i += gridDim.x * 256) {
        int m = i >> 10;
        int c = i & 1023;
        int t = m >> 4;
        int b = m & 15;
        float v;
        if (c < 512) {
            int w = helper[b * Tc + t];
            v = emb[(size_t)w * Ec + c];
        } else {
            v = init[b * Ec + (c - 512)];
        }
        X0[i] = v;
    }
}

// ---------------------------------------------------------------------------
// h0 one-step GRU with zero initial state. dup=1 -> input row is [init;init]
// ---------------------------------------------------------------------------
__global__ __launch_bounds__(256) void h0_layer(const float* __restrict__ xin,
                                                const float* __restrict__ Wih,
                                                const float* __restrict__ bih,
                                                const float* __restrict__ bhh,
                                                float* __restrict__ h0out, int dup) {
    __shared__ float xs[1024];
    int b = blockIdx.x >> 2;
    int hseg = blockIdx.x & 3;
    int tid = threadIdx.x;
    for (int i = tid; i < 1024; i += 256)
        xs[i] = dup ? xin[b * 512 + (i & 511)] : xin[b * 1024 + i];
    __syncthreads();
    int hidx = hseg * 256 + tid;
    const float* wr = Wih + (size_t)hidx * 1024;
    const float* wz = Wih + (size_t)(Hc + hidx) * 1024;
    const float* wn = Wih + (size_t)(2 * Hc + hidx) * 1024;
    float ar = 0.f, az = 0.f, an = 0.f;
    for (int k = 0; k < 1024; k += 4) {
        float4 x4 = *(const float4*)&xs[k];
        ar += dot4(*(const float4*)&wr[k], x4);
        az += dot4(*(const float4*)&wz[k], x4);
        an += dot4(*(const float4*)&wn[k], x4);
    }
    float r = sigm(ar + bih[hidx] + bhh[hidx]);
    float z = sigm(az + bih[Hc + hidx] + bhh[Hc + hidx]);
    float n = tanhf(an + bih[2 * Hc + hidx] + r * bhh[2 * Hc + hidx]);
    h0out[b * Hc + hidx] = (1.f - z) * n;  // h_old = 0
}

// ---------------------------------------------------------------------------
// Fused 64-step GRU scan, v2. 256 blocks x 512 threads (8 waves/CU; 88 KB
// LDS incl. dynamic pad forces exactly 1 block/CU -> guaranteed co-residency).
// Block k owns h-indices [4k,4k+4); 12 W_hh rows in LDS for the whole scan.
// Thread map: b = tid>>5 (batch), kseg = tid&31 (32 floats of k, float2-
// interleaved stride 256B -> coalesced h loads; lanes l and l+32 read the
// SAME W address -> LDS broadcast). Reduction over kseg = 5-step shfl_xor
// butterfly (no LDS round-trip, no 2nd barrier). Reducer lane (kseg==0 per
// b) keeps h_old in registers, prefetches xp as 3x float4, computes 4 gates.
// Inter-step sync: tree barrier (16 leaf counters 128B apart + root) via
// agent-scope relaxed atomics; h exchanged through L3 with sc0 sc1 ops.
// ys: slot s at ys + s*16384 (slot 0 = h0, slot t+1 = h after step t).
// ---------------------------------------------------------------------------
__global__ __launch_bounds__(512) void gru_scan(const float* __restrict__ xp,
                                                const float* __restrict__ Whh,
                                                const float* __restrict__ bhh,
                                                float* __restrict__ ys,
                                                unsigned* __restrict__ bar) {
    extern __shared__ char lds_pad[];  // dynamic pad: forces 1 block/CU
    __shared__ float wlds[12][1024];   // [hl*3+gate][k]  48 KB
    int tid = threadIdx.x;
    int g0 = blockIdx.x * 4;

    // stage 12 W_hh rows (gate-major: row = gate*H + g0+hl) into LDS
    for (int i = tid; i < 12 * 256; i += 512) {
        int r = i >> 8, c = i & 255;
        int hl = r / 3, gate = r % 3;
        ((float4*)wlds[r])[c] =
            ((const float4*)&Whh[(size_t)(gate * Hc + g0 + hl) * Hc])[c];
    }

    int b = tid >> 5;     // batch 0..15
    int kseg = tid & 31;  // k-segment 0..31

    // reducer-lane persistent state
    float bh[12];
    float hold[4];
    if (kseg == 0) {
#pragma unroll
        for (int r = 0; r < 12; ++r) {
            int hl = r / 3, gate = r % 3;
            bh[r] = bhh[gate * Hc + g0 + hl];
        }
        float4 h4 = *(const float4*)&ys[b * Hc + g0];  // slot 0 = h0
        hold[0] = h4.x; hold[1] = h4.y; hold[2] = h4.z; hold[3] = h4.w;
    }
    __syncthreads();

    unsigned* leaf = bar + (blockIdx.x & 15) * 32;  // 128 B apart
    unsigned* root = bar + 512;

    for (int t = 0; t < Tc; ++t) {
        // prefetch xp gate values for this (t, b): 3 gates x 4 h-idx
        float xg[3][4];
        if (kseg == 0) {
            const float* xrow = xp + (size_t)(t * Bc + b) * 3072 + g0;
#pragma unroll
            for (int gte = 0; gte < 3; ++gte) {
                float4 v = *(const float4*)&xrow[gte * 1024];
                xg[gte][0] = v.x; xg[gte][1] = v.y; xg[gte][2] = v.z; xg[gte][3] = v.w;
            }
        }
        // coherent h load: 16 x 8B, interleaved (lane-consecutive 8B runs)
        const unsigned long long* hsrc =
            (const unsigned long long*)(ys + (size_t)t * (Bc * Hc)) + b * 512 + kseg;
        float2 hv[16];
#pragma unroll
        for (int q = 0; q < 16; ++q)
            hv[q] = u2f2(__hip_atomic_load(hsrc + q * 32, __ATOMIC_RELAXED,
                                           __HIP_MEMORY_SCOPE_AGENT));
        // MAC against LDS weights (broadcast across the two b's of a wave)
        float acc[12];
#pragma unroll
        for (int r = 0; r < 12; ++r) {
            const float2* w = (const float2*)&wlds[r][kseg * 2];
            float s = 0.f;
#pragma unroll
            for (int q = 0; q < 16; ++q) {
                float2 ww = w[q * 32];  // +256B per q
                s += ww.x * hv[q].x + ww.y * hv[q].y;
            }
            acc[r] = s;
        }
        // butterfly reduce over 32 ksegs (stays within 32-lane half-wave)
#pragma unroll
        for (int r = 0; r < 12; ++r) {
            float s = acc[r];
            s += __shfl_xor(s, 1);
            s += __shfl_xor(s, 2);
            s += __shfl_xor(s, 4);
            s += __shfl_xor(s, 8);
            s += __shfl_xor(s, 16);
            acc[r] = s;
        }
        if (kseg == 0) {
            float hnew[4];
#pragma unroll
            for (int hl = 0; hl < 4; ++hl) {
                float r_ = sigm(xg[0][hl] + acc[hl * 3 + 0] + bh[hl * 3 + 0]);
                float z_ = sigm(xg[1][hl] + acc[hl * 3 + 1] + bh[hl * 3 + 1]);
                float n_ = tanhf(xg[2][hl] + r_ * (acc[hl * 3 + 2] + bh[hl * 3 + 2]));
                hnew[hl] = (1.f - z_) * n_ + z_ * hold[hl];
                hold[hl] = hnew[hl];
            }
            unsigned long long* dst =
                (unsigned long long*)(ys + (size_t)(t + 1) * (Bc * Hc) + b * Hc + g0);
            __hip_atomic_store(dst, f22u(hnew[0], hnew[1]), __ATOMIC_RELAXED,
                               __HIP_MEMORY_SCOPE_AGENT);
            __hip_atomic_store(dst + 1, f22u(hnew[2], hnew[3]), __ATOMIC_RELAXED,
                               __HIP_MEMORY_SCOPE_AGENT);
        }
        if (t < Tc - 1) {
            __syncthreads();  // drains vmcnt: h stores globally visible
            if (tid == 0) {
                unsigned old = __hip_atomic_fetch_add(leaf, 1u, __ATOMIC_RELAXED,
                                                      __HIP_MEMORY_SCOPE_AGENT);
                if (old == (unsigned)(t * 16 + 15))
                    __hip_atomic_fetch_add(root, 1u, __ATOMIC_RELAXED,
                                           __HIP_MEMORY_SCOPE_AGENT);
                unsigned tgt = (unsigned)((t + 1) * 16);
                while (__hip_atomic_load(root, __ATOMIC_RELAXED,
                                         __HIP_MEMORY_SCOPE_AGENT) < tgt)
                    __builtin_amdgcn_s_sleep(1);
            }
            __syncthreads();
        }
    }
}

// ---------------------------------------------------------------------------
// Split-bf16 MFMA GEMM (fp32-accurate): C = act( A @ B^T + bias ), where
// A = Ah + Al, B = Bh + Bl and C = Ah Bh + Ah Bl + Al Bh (3 phases).
// 128x128 tile, BK=32, 4 waves in 2x2, 16x16x32 bf16 MFMA.
// remap=1: output row m=t*B+b stored at row b*T+t. N edge guarded.
// ---------------------------------------------------------------------------
#define GLD_LDS16(g, l)                                                        \
    __builtin_amdgcn_global_load_lds(                                          \
        (const __attribute__((address_space(1))) unsigned int*)(g),            \
        (__attribute__((address_space(3))) unsigned int*)(l), 16, 0, 0)

__global__ __launch_bounds__(256) void mfma_gemm_split(
    const unsigned short* __restrict__ Ah, const unsigned short* __restrict__ Al,
    const unsigned short* __restrict__ Bh, const unsigned short* __restrict__ Bl,
    const float* __restrict__ bias, float* __restrict__ C, int N, int K, int ldc,
    int act, int remap) {
    __shared__ __align__(16) unsigned short As[128 * 32];  // [m][k] 8 KB
    __shared__ __align__(16) unsigned short Bs[128 * 32];  // [n][k] 8 KB
    int tid = threadIdx.x;
    int m0 = blockIdx.y * 128, n0 = blockIdx.x * 128;
    int wave = tid >> 6, lane = tid & 63;
    int mh = (wave >> 1) * 64, nh = (wave & 1) * 64;
    int rlane = lane & 15, k8 = (lane >> 4) * 8;

    f32x4 zero = {0.f, 0.f, 0.f, 0.f};
    f32x4 acc[4][4];
#pragma unroll
    for (int i = 0; i < 4; ++i)
#pragma unroll
        for (int j = 0; j < 4; ++j) acc[i][j] = zero;

    const unsigned short* Ap[3] = {Ah, Al, Ah};
    const unsigned short* Bp[3] = {Bh, Bh, Bl};

    int c0 = tid, c1 = tid + 256;
    int ar0 = m0 + (c0 >> 2), ak0 = (c0 & 3) * 8;
    int ar1 = m0 + (c1 >> 2), ak1 = (c1 & 3) * 8;
    int br0 = n0 + (c0 >> 2);
    int br1 = n0 + (c1 >> 2);
    if (br0 >= N) br0 = N - 1;
    if (br1 >= N) br1 = N - 1;

    for (int ph = 0; ph < 3; ++ph) {
        const unsigned short* Ab = Ap[ph];
        const unsigned short* Bb = Bp[ph];
        for (int kt = 0; kt < K; kt += 32) {
            GLD_LDS16(&Ab[(size_t)ar0 * K + kt + ak0], &As[c0 * 8]);
            GLD_LDS16(&Ab[(size_t)ar1 * K + kt + ak1], &As[c1 * 8]);
            GLD_LDS16(&Bb[(size_t)br0 * K + kt + ak0], &Bs[c0 * 8]);
            GLD_LDS16(&Bb[(size_t)br1 * K + kt + ak1], &Bs[c1 * 8]);
            __syncthreads();
            bf16x8 a[4], b[4];
#pragma unroll
            for (int f = 0; f < 4; ++f)
                a[f] = *(const bf16x8*)&As[(mh + f * 16 + rlane) * 32 + k8];
#pragma unroll
            for (int f = 0; f < 4; ++f)
                b[f] = *(const bf16x8*)&Bs[(nh + f * 16 + rlane) * 32 + k8];
#pragma unroll
            for (int mf = 0; mf < 4; ++mf)
#pragma unroll
                for (int nf = 0; nf < 4; ++nf)
                    acc[mf][nf] = __builtin_amdgcn_mfma_f32_16x16x32_bf16(
                        a[mf], b[nf], acc[mf][nf], 0, 0, 0);
            __syncthreads();
        }
    }

    int quad = lane >> 4;
#pragma unroll
    for (int nf = 0; nf < 4; ++nf) {
        int n = n0 + nh + nf * 16 + rlane;
        if (n >= N) continue;
        float bv = bias ? bias[n] : 0.f;
#pragma unroll
        for (int mf = 0; mf < 4; ++mf) {
#pragma unroll
            for (int r = 0; r < 4; ++r) {
                int m = m0 + mh + mf * 16 + quad * 4 + r;
                float x = acc[mf][nf][r] + bv;
                if (act) x = tanhf(x);
                int orow = remap ? ((m & 15) * Tc + (m >> 4)) : m;
                C[(size_t)orow * ldc + n] = x;
            }
        }
    }
}

// ---------------------------------------------------------------------------
extern "C" void kernel_launch(void* const* d_in, const int* in_sizes, int n_in,
                              void* d_out, int out_size, void* d_ws, size_t ws_size,
                              hipStream_t stream) {
    const float* init   = (const float*)d_in[0];
    const int*   helper = (const int*)d_in[1];
    const float* emb    = (const float*)d_in[2];
    const float* W_ih0  = (const float*)d_in[3];
    const float* W_hh0  = (const float*)d_in[4];
    const float* b_ih0  = (const float*)d_in[5];
    const float* b_hh0  = (const float*)d_in[6];
    const float* W_ih1  = (const float*)d_in[7];
    const float* W_hh1  = (const float*)d_in[8];
    const float* b_ih1  = (const float*)d_in[9];
    const float* b_hh1  = (const float*)d_in[10];
    const float* Wc_w   = (const float*)d_in[11];
    const float* Wc_b   = (const float*)d_in[12];
    float* out = (float*)d_out;

    const int embN = Vc * Ec;

    char* p = (char*)d_ws;
    auto alloc = [&](size_t bytes) {
        char* r = p;
        p += (bytes + 255) & ~(size_t)255;
        return r;
    };
    float* X0   = (float*)alloc((size_t)1048576 * 4);
    float* xp0  = (float*)alloc((size_t)3145728 * 4);
    float* xp1  = (float*)alloc((size_t)3145728 * 4);
    float* ys0x = (float*)alloc((size_t)65 * 16384 * 4);
    float* ys1x = (float*)alloc((size_t)65 * 16384 * 4);
    float* fin  = (float*)alloc((size_t)524288 * 4);
    unsigned* bar = (unsigned*)alloc(8192);
    unsigned short* embh = (unsigned short*)alloc((size_t)embN * 2);
    unsigned short* embl = (unsigned short*)alloc((size_t)embN * 2);
    unsigned short* X0h  = (unsigned short*)alloc((size_t)1048576 * 2);
    unsigned short* X0l  = (unsigned short*)alloc((size_t)1048576 * 2);
    unsigned short* Wi0h = (unsigned short*)alloc((size_t)3145728 * 2);
    unsigned short* Wi0l = (unsigned short*)alloc((size_t)3145728 * 2);
    unsigned short* Wi1h = (unsigned short*)alloc((size_t)3145728 * 2);
    unsigned short* Wi1l = (unsigned short*)alloc((size_t)3145728 * 2);
    unsigned short* Wch  = (unsigned short*)alloc((size_t)524288 * 2);
    unsigned short* Wcl  = (unsigned short*)alloc((size_t)524288 * 2);
    unsigned short* ys0h = (unsigned short*)alloc((size_t)1048576 * 2);
    unsigned short* ys0l = (unsigned short*)alloc((size_t)1048576 * 2);
    unsigned short* ys1h = (unsigned short*)alloc((size_t)1048576 * 2);
    unsigned short* ys1l = (unsigned short*)alloc((size_t)1048576 * 2);
    unsigned short* finh = (unsigned short*)alloc((size_t)524288 * 2);
    unsigned short* finl = (unsigned short*)alloc((size_t)524288 * 2);

    hipMemsetAsync(bar, 0, 8192, stream);

    auto split = [&](const float* src, unsigned short* h, unsigned short* l, int n) {
        int n4 = n / 4;
        int grid = (n4 + 255) / 256;
        if (grid > 4096) grid = 4096;
        split_bf16_4<<<grid, 256, 0, stream>>>((const float4*)src, (ushort4*)h,
                                               (ushort4*)l, n4);
    };

    split(emb, embh, embl, embN);
    split(W_ih0, Wi0h, Wi0l, 3145728);
    split(W_ih1, Wi1h, Wi1l, 3145728);
    split(Wc_w, Wch, Wcl, 524288);

    h0_layer<<<64, 256, 0, stream>>>(init, W_ih0, b_ih0, b_hh0, ys0x, 1);
    h0_layer<<<64, 256, 0, stream>>>(ys0x, W_ih1, b_ih1, b_hh1, ys1x, 0);

    build_x0<<<1024, 256, 0, stream>>>(emb, helper, init, X0);
    split(X0, X0h, X0l, 1048576);
    mfma_gemm_split<<<dim3(24, 8), 256, 0, stream>>>(X0h, X0l, Wi0h, Wi0l, b_ih0,
                                                     xp0, 3072, 1024, 3072, 0, 0);
    gru_scan<<<SCAN_BLOCKS, 512, 40960, stream>>>(xp0, W_hh0, b_hh0, ys0x, bar);

    split(ys0x + 16384, ys0h, ys0l, 1048576);
    mfma_gemm_split<<<dim3(24, 8), 256, 0, stream>>>(ys0h, ys0l, Wi1h, Wi1l, b_ih1,
                                                     xp1, 3072, 1024, 3072, 0, 0);
    gru_scan<<<SCAN_BLOCKS, 512, 40960, stream>>>(xp1, W_hh1, b_hh1, ys1x, bar + 1024);

    split(ys1x + 16384, ys1h, ys1l, 1048576);
    mfma_gemm_split<<<dim3(4, 8), 256, 0, stream>>>(ys1h, ys1l, Wch, Wcl, Wc_b,
                                                    fin, 512, 1024, 512, 1, 0);

    split(fin, finh, finl, 524288);
    mfma_gemm_split<<<dim3((Vc + 127) / 128, 8), 256, 0, stream>>>(
        finh, finl, embh, embl, nullptr, out, Vc, 512, Vc, 0, 1);
}